// Round 13
// baseline (102.162 us; speedup 1.0000x reference)
//
#include <hip/hip_runtime.h>

// uLSIF loss: out = mean_i[ -2*exp(x_i.a_i/T) + (sum_j exp(2*x_i.a_j/T) - exp(2*x_i.a_i/T))/(N-1) ]
// N=8192, D=128, T=128.
// r5/r8/r11 post-mortem: three different gemm schedules all ~30us -> schedule is not the
// bottleneck; common factors were mega-unrolled body (I-cache) + register pressure (spills).
// This round: compact ROLLED gemm loop (#pragma unroll 1, ~3.6KB body) + lean registers
// (wave tile 64x32: acc 32 + afr 64 + B dbuf 64 ~= 185 VGPR, no spill).
// conv_diag: fused fp32->f16 fragment-major pack (a scaled by C2) + exact fp32/f64 diagonal.
// gemm: A-frags reg-cached; B-frags global->reg double-buffered per 64-col step.
// finalize: sums all per-block partials. No same-address atomics, no LDS staging.

#define NN 8192
#define DD 128

typedef __attribute__((ext_vector_type(4))) float f32x4;
typedef __attribute__((ext_vector_type(8))) _Float16 f16x8;

// ---------------- fused pack (fragment-major f16) + exact diagonal ---------------
// Fragment layout: frag f = rg*4 + ks (rg = 16-row group, ks = 32-f16 k group).
// Lane l holds row rg*16+(l&15), k = ks*32 + (l>>4)*8 .. +8. Byte addr f*1024 + l*16.
// Thread i (0..262143) owns float4 col q=i&31 of row i>>5 in BOTH x and a:
//   ks = q>>3, lane = ((q&7)>>1)<<4 | (row&15), byte off += (i&1)*8 (ushort4 store).
__global__ void conv_diag_kernel(const float4* __restrict__ x, const float4* __restrict__ a,
                                 char* __restrict__ xf, char* __restrict__ af,
                                 double* __restrict__ s1p, double* __restrict__ s3p) {
    const float C2 = (float)(2.0 / (128.0 * 0.69314718055994530942));
    int t = threadIdx.x;
    int i = blockIdx.x * 256 + t;                 // 0..262143
    int row = i >> 5;
    int q   = i & 31;
    int ks  = q >> 3;
    int l   = (((q & 7) >> 1) << 4) | (row & 15);
    int f   = (row >> 4) * 4 + ks;
    size_t off = (size_t)f * 1024 + (size_t)l * 16 + (size_t)(i & 1) * 8;

    float4 xv = x[i];
    float4 av = a[i];
    ushort4 xu, au;
    xu.x = __builtin_bit_cast(unsigned short, (_Float16)xv.x);
    xu.y = __builtin_bit_cast(unsigned short, (_Float16)xv.y);
    xu.z = __builtin_bit_cast(unsigned short, (_Float16)xv.z);
    xu.w = __builtin_bit_cast(unsigned short, (_Float16)xv.w);
    au.x = __builtin_bit_cast(unsigned short, (_Float16)(av.x * C2));
    au.y = __builtin_bit_cast(unsigned short, (_Float16)(av.y * C2));
    au.z = __builtin_bit_cast(unsigned short, (_Float16)(av.z * C2));
    au.w = __builtin_bit_cast(unsigned short, (_Float16)(av.w * C2));
    *(ushort4*)(xf + off) = xu;
    *(ushort4*)(af + off) = au;

    // exact fp32 diagonal: 32 consecutive threads cover one row
    float d = xv.x * av.x + xv.y * av.y + xv.z * av.z + xv.w * av.w;
#pragma unroll
    for (int o = 16; o > 0; o >>= 1) d += __shfl_down(d, o, 32);

    __shared__ double rr[8];
    if ((t & 31) == 0) rr[t >> 5] = exp((double)d * (1.0 / 128.0));
    __syncthreads();
    if (t == 0) {
        double s1 = 0.0, s3 = 0.0;
#pragma unroll
        for (int k = 0; k < 8; ++k) { s1 += rr[k]; s3 += rr[k] * rr[k]; }
        s1p[blockIdx.x] = s1;
        s3p[blockIdx.x] = s3;
    }
}

// ---------------- fused GEMM + exp2 + sum: compact rolled loop -------------------
// grid = 32 row-panels x 8 col-chunks = 256 blocks, 512 thr (8 waves = 4m x 2n).
// Wave: 64 rows x 32 cols per step; 16 steps of 64 block-cols cover the 1024-col chunk.
// A-frags (4mi x 4ks) reg-cached once. B-frags double-buffered (2ni x 4ks per buffer).
// NOTE chunk = blockIdx&7: under %8 XCD round-robin, all 32 blocks sharing a B-chunk
// land on one XCD -> chunk (1MB) + their A panels fit that XCD's 4MB L2.
__global__ __launch_bounds__(512, 2) void gemm_exp_sum(const f16x8* __restrict__ xf,
                                                       const f16x8* __restrict__ af,
                                                       double* __restrict__ s2p) {
    const int tid  = threadIdx.x;
    const int lane = tid & 63;
    const int wid  = tid >> 6;
    const int bm    = blockIdx.x >> 3;   // 32 row panels of 256
    const int chunk = blockIdx.x & 7;    // 8 col chunks of 1024
    const int wm = wid >> 1;             // 0..3
    const int wn = wid & 1;              // 0..1

    // ---- A fragments, loaded once: rows bm*256 + wm*64 + mi*16 ----
    const int fA0 = (bm * 16 + wm * 4) * 4;          // + mi*4 + ks
    f16x8 afr[4][4];
#pragma unroll
    for (int mi = 0; mi < 4; ++mi)
#pragma unroll
        for (int ks = 0; ks < 4; ++ks)
            afr[mi][ks] = xf[(size_t)(fA0 + mi * 4 + ks) * 64 + lane];

    // B frag index for step s, sub-col ni: ((chunk*64 + s*4 + wn*2 + ni)*4 + ks)
    const int fB0 = (chunk * 64 + wn * 2) * 4;       // + s*16 + ni*4 + ks

    f16x8 b0[2][4], b1[2][4];
#pragma unroll
    for (int ni = 0; ni < 2; ++ni)
#pragma unroll
        for (int ks = 0; ks < 4; ++ks)
            b0[ni][ks] = af[(size_t)(fB0 + ni * 4 + ks) * 64 + lane];

    f32x4 acc[4][2];
    float ls0 = 0.f, ls1 = 0.f, ls2 = 0.f, ls3 = 0.f;

#define PREFETCH(B, S)                                                              \
    {                                                                               \
        const int sc = (S) > 15 ? 15 : (S);                                         \
        _Pragma("unroll") for (int ni = 0; ni < 2; ++ni)                            \
            _Pragma("unroll") for (int ks = 0; ks < 4; ++ks)                        \
                B[ni][ks] = af[(size_t)(fB0 + sc * 16 + ni * 4 + ks) * 64 + lane];  \
    }

#define COMPUTE(B)                                                                  \
    {                                                                               \
        _Pragma("unroll") for (int mi = 0; mi < 4; ++mi)                            \
            _Pragma("unroll") for (int ni = 0; ni < 2; ++ni)                        \
                acc[mi][ni] = f32x4{0.f, 0.f, 0.f, 0.f};                            \
        _Pragma("unroll") for (int ks = 0; ks < 4; ++ks)                            \
            _Pragma("unroll") for (int mi = 0; mi < 4; ++mi)                        \
                _Pragma("unroll") for (int ni = 0; ni < 2; ++ni)                    \
                    acc[mi][ni] = __builtin_amdgcn_mfma_f32_16x16x32_f16(           \
                        afr[mi][ks], B[ni][ks], acc[mi][ni], 0, 0, 0);              \
        _Pragma("unroll") for (int mi = 0; mi < 4; ++mi)                            \
            _Pragma("unroll") for (int ni = 0; ni < 2; ++ni) {                      \
                ls0 += __builtin_amdgcn_exp2f(acc[mi][ni][0]);                      \
                ls1 += __builtin_amdgcn_exp2f(acc[mi][ni][1]);                      \
                ls2 += __builtin_amdgcn_exp2f(acc[mi][ni][2]);                      \
                ls3 += __builtin_amdgcn_exp2f(acc[mi][ni][3]);                      \
            }                                                                       \
    }

#pragma unroll 1
    for (int s = 0; s < 16; s += 2) {
        PREFETCH(b1, s + 1);
        COMPUTE(b0);
        PREFETCH(b0, s + 2);
        COMPUTE(b1);
    }
#undef PREFETCH
#undef COMPUTE

    float lsum = (ls0 + ls1) + (ls2 + ls3);
#pragma unroll
    for (int o = 32; o > 0; o >>= 1) lsum += __shfl_down(lsum, o);

    __shared__ double wred[8];
    if (lane == 0) wred[wid] = (double)lsum;
    __syncthreads();
    if (tid == 0) {
        double s = 0.0;
#pragma unroll
        for (int k = 0; k < 8; ++k) s += wred[k];
        s2p[blockIdx.x] = s;
    }
}

// ---------------- finalize: sum all partials -------------------------------------
__global__ void finalize_kernel(const double* __restrict__ s1p, const double* __restrict__ s3p,
                                const double* __restrict__ s2p, float* __restrict__ out) {
    int t = threadIdx.x;                // 1024 threads
    double v1 = s1p[t];
    double v3 = s3p[t];
    double v2 = (t < 256) ? s2p[t] : 0.0;
#pragma unroll
    for (int o = 32; o > 0; o >>= 1) {
        v1 += __shfl_down(v1, o);
        v3 += __shfl_down(v3, o);
        v2 += __shfl_down(v2, o);
    }
    __shared__ double r1[16], r2[16], r3[16];
    int wid = t >> 6, lane = t & 63;
    if (lane == 0) { r1[wid] = v1; r2[wid] = v2; r3[wid] = v3; }
    __syncthreads();
    if (t == 0) {
        double S1 = 0.0, S2 = 0.0, S3 = 0.0;
#pragma unroll
        for (int k = 0; k < 16; ++k) { S1 += r1[k]; S2 += r2[k]; S3 += r3[k]; }
        double res = (-2.0 * S1 + (S2 - S3) / (double)(NN - 1)) / (double)NN;
        out[0] = (float)res;
    }
}

extern "C" void kernel_launch(void* const* d_in, const int* in_sizes, int n_in,
                              void* d_out, int out_size, void* d_ws, size_t ws_size,
                              hipStream_t stream) {
    const float* x = (const float*)d_in[0];
    const float* a = (const float*)d_in[1];
    float* out = (float*)d_out;
    char* ws = (char*)d_ws;

    double* s1p = (double*)ws;                      // 1024 f64 = 8 KB
    double* s3p = (double*)(ws + 8192);             // 1024 f64 = 8 KB
    double* s2p = (double*)(ws + 16384);            // 256  f64 = 2 KB
    char*   xf  = ws + 32768;                       // 2 MB packed f16 x
    char*   af  = ws + 32768 + (size_t)NN * DD * 2; // 2 MB packed f16 a*C2

    conv_diag_kernel<<<1024, 256, 0, stream>>>((const float4*)x, (const float4*)a,
                                               xf, af, s1p, s3p);
    gemm_exp_sum<<<256, 512, 0, stream>>>((const f16x8*)xf, (const f16x8*)af, s2p);
    finalize_kernel<<<1, 1024, 0, stream>>>(s1p, s3p, s2p, out);
}

// Round 16
// 83.626 us; speedup vs baseline: 1.2217x; 1.2217x over previous
//
#include <hip/hip_runtime.h>

// uLSIF loss: out = mean_i[ -2*exp(x_i.a_i/T) + (sum_j exp(2*x_i.a_j/T) - exp(2*x_i.a_i/T))/(N-1) ]
// N=8192, D=128, T=128.
// r5/r8/r11/r13 post-mortem: gemm stuck ~35us across 3 schedules; pipes idle; occupancy
// ~2 waves/SIMD; cold-L2 latency unhidden. Diagnosis: LATENCY/OCCUPANCY-bound.
// This round: 4 waves/SIMD (grid 1024 x 256thr, launch_bounds(256,4), ~100 VGPR),
// wave tile 32x32, full unroll (r13 showed rolling hurts), block's 4 waves share B cols
// (L1 reuse), bijective XCD swizzle (each XCD: 8 A-panels + all B = 2.25MB < 4MB L2).
// conv_diag: fused fragment-major f16 pack (a scaled by C2) + exact fp32/f64 diagonal.
// finalize: sums per-block partials. No atomics, no LDS staging, no barriers in gemm.

#define NN 8192
#define DD 128

typedef __attribute__((ext_vector_type(4))) float f32x4;
typedef __attribute__((ext_vector_type(8))) _Float16 f16x8;

// ---------------- fused pack (fragment-major f16) + exact diagonal ---------------
// Fragment layout: frag f = rg*4 + ks (rg = 16-row group, ks = 32-f16 k group).
// Lane l holds row rg*16+(l&15), k = ks*32 + (l>>4)*8 .. +8. Byte addr f*1024 + l*16.
// Thread i (0..262143) owns float4 col q=i&31 of row i>>5 in BOTH x and a:
//   ks = q>>3, lane = ((q&7)>>1)<<4 | (row&15), byte off += (i&1)*8 (ushort4 store).
__global__ void conv_diag_kernel(const float4* __restrict__ x, const float4* __restrict__ a,
                                 char* __restrict__ xf, char* __restrict__ af,
                                 double* __restrict__ s1p, double* __restrict__ s3p) {
    const float C2 = (float)(2.0 / (128.0 * 0.69314718055994530942));
    int t = threadIdx.x;
    int i = blockIdx.x * 256 + t;                 // 0..262143
    int row = i >> 5;
    int q   = i & 31;
    int ks  = q >> 3;
    int l   = (((q & 7) >> 1) << 4) | (row & 15);
    int f   = (row >> 4) * 4 + ks;
    size_t off = (size_t)f * 1024 + (size_t)l * 16 + (size_t)(i & 1) * 8;

    float4 xv = x[i];
    float4 av = a[i];
    ushort4 xu, au;
    xu.x = __builtin_bit_cast(unsigned short, (_Float16)xv.x);
    xu.y = __builtin_bit_cast(unsigned short, (_Float16)xv.y);
    xu.z = __builtin_bit_cast(unsigned short, (_Float16)xv.z);
    xu.w = __builtin_bit_cast(unsigned short, (_Float16)xv.w);
    au.x = __builtin_bit_cast(unsigned short, (_Float16)(av.x * C2));
    au.y = __builtin_bit_cast(unsigned short, (_Float16)(av.y * C2));
    au.z = __builtin_bit_cast(unsigned short, (_Float16)(av.z * C2));
    au.w = __builtin_bit_cast(unsigned short, (_Float16)(av.w * C2));
    *(ushort4*)(xf + off) = xu;
    *(ushort4*)(af + off) = au;

    // exact fp32 diagonal: 32 consecutive threads cover one row
    float d = xv.x * av.x + xv.y * av.y + xv.z * av.z + xv.w * av.w;
#pragma unroll
    for (int o = 16; o > 0; o >>= 1) d += __shfl_down(d, o, 32);

    __shared__ double rr[8];
    if ((t & 31) == 0) rr[t >> 5] = exp((double)d * (1.0 / 128.0));
    __syncthreads();
    if (t == 0) {
        double s1 = 0.0, s3 = 0.0;
#pragma unroll
        for (int k = 0; k < 8; ++k) { s1 += rr[k]; s3 += rr[k] * rr[k]; }
        s1p[blockIdx.x] = s1;
        s3p[blockIdx.x] = s3;
    }
}

// ---------------- fused GEMM + exp2 + sum: high-occupancy streaming --------------
// grid = 64 row-panels(128r) x 16 col-chunks(512c) = 1024 blocks, 256 thr (4 waves).
// Wave wm owns rows wm*32..+32 of the panel; all 4 waves share the chunk's B cols
// (L1 reuse). Per step: 32 cols -> 16 MFMA + 8 B-loads + 16 exp2 per wave.
// 4 blocks/CU (launch_bounds 256,4) = 16 waves/CU = 4 waves/SIMD for latency hiding.
__global__ __launch_bounds__(256, 4) void gemm_exp_sum(const f16x8* __restrict__ xf,
                                                       const f16x8* __restrict__ af,
                                                       double* __restrict__ s2p) {
    const int tid  = threadIdx.x;
    const int lane = tid & 63;
    const int wm   = tid >> 6;                       // 0..3
    // bijective XCD swizzle (1024 % 8 == 0): XCD k gets panels k*8..k*8+7, all chunks
    const int wg    = (blockIdx.x & 7) * 128 + (blockIdx.x >> 3);
    const int panel = wg >> 4;                       // 0..63
    const int chunk = wg & 15;                       // 0..15

    // ---- A fragments, loaded once: rows panel*128 + wm*32 + mi*16 ----
    const int fA0 = (panel * 8 + wm * 2) * 4;        // + mi*4 + ks
    f16x8 afr[2][4];
#pragma unroll
    for (int mi = 0; mi < 2; ++mi)
#pragma unroll
        for (int ks = 0; ks < 4; ++ks)
            afr[mi][ks] = xf[(size_t)(fA0 + mi * 4 + ks) * 64 + lane];

    // B frag for step s, ni: (chunk*32 + s*2 + ni)*4 + ks
    const int fB0 = chunk * 128;                     // (chunk*32)*4
    float ls0 = 0.f, ls1 = 0.f, ls2 = 0.f, ls3 = 0.f;

#pragma unroll
    for (int s = 0; s < 16; ++s) {
        f16x8 b[2][4];
#pragma unroll
        for (int ni = 0; ni < 2; ++ni)
#pragma unroll
            for (int ks = 0; ks < 4; ++ks)
                b[ni][ks] = af[(size_t)(fB0 + (s * 2 + ni) * 4 + ks) * 64 + lane];

        f32x4 acc[2][2];
#pragma unroll
        for (int mi = 0; mi < 2; ++mi)
#pragma unroll
            for (int ni = 0; ni < 2; ++ni) acc[mi][ni] = f32x4{0.f, 0.f, 0.f, 0.f};

#pragma unroll
        for (int ks = 0; ks < 4; ++ks)
#pragma unroll
            for (int mi = 0; mi < 2; ++mi)
#pragma unroll
                for (int ni = 0; ni < 2; ++ni)
                    acc[mi][ni] = __builtin_amdgcn_mfma_f32_16x16x32_f16(
                        afr[mi][ks], b[ni][ks], acc[mi][ni], 0, 0, 0);

#pragma unroll
        for (int mi = 0; mi < 2; ++mi)
#pragma unroll
            for (int ni = 0; ni < 2; ++ni) {
                ls0 += __builtin_amdgcn_exp2f(acc[mi][ni][0]);
                ls1 += __builtin_amdgcn_exp2f(acc[mi][ni][1]);
                ls2 += __builtin_amdgcn_exp2f(acc[mi][ni][2]);
                ls3 += __builtin_amdgcn_exp2f(acc[mi][ni][3]);
            }
    }

    float lsum = (ls0 + ls1) + (ls2 + ls3);
#pragma unroll
    for (int o = 32; o > 0; o >>= 1) lsum += __shfl_down(lsum, o);

    __shared__ double wred[4];
    if (lane == 0) wred[wm] = (double)lsum;
    __syncthreads();
    if (tid == 0)
        s2p[blockIdx.x] = (wred[0] + wred[1]) + (wred[2] + wred[3]);
}

// ---------------- finalize: sum all partials -------------------------------------
__global__ void finalize_kernel(const double* __restrict__ s1p, const double* __restrict__ s3p,
                                const double* __restrict__ s2p, float* __restrict__ out) {
    int t = threadIdx.x;                // 1024 threads
    double v1 = s1p[t];
    double v3 = s3p[t];
    double v2 = s2p[t];
#pragma unroll
    for (int o = 32; o > 0; o >>= 1) {
        v1 += __shfl_down(v1, o);
        v3 += __shfl_down(v3, o);
        v2 += __shfl_down(v2, o);
    }
    __shared__ double r1[16], r2[16], r3[16];
    int wid = t >> 6, lane = t & 63;
    if (lane == 0) { r1[wid] = v1; r2[wid] = v2; r3[wid] = v3; }
    __syncthreads();
    if (t == 0) {
        double S1 = 0.0, S2 = 0.0, S3 = 0.0;
#pragma unroll
        for (int k = 0; k < 16; ++k) { S1 += r1[k]; S2 += r2[k]; S3 += r3[k]; }
        double res = (-2.0 * S1 + (S2 - S3) / (double)(NN - 1)) / (double)NN;
        out[0] = (float)res;
    }
}

extern "C" void kernel_launch(void* const* d_in, const int* in_sizes, int n_in,
                              void* d_out, int out_size, void* d_ws, size_t ws_size,
                              hipStream_t stream) {
    const float* x = (const float*)d_in[0];
    const float* a = (const float*)d_in[1];
    float* out = (float*)d_out;
    char* ws = (char*)d_ws;

    double* s1p = (double*)ws;                      // 1024 f64 = 8 KB
    double* s3p = (double*)(ws + 8192);             // 1024 f64 = 8 KB
    double* s2p = (double*)(ws + 16384);            // 1024 f64 = 8 KB
    char*   xf  = ws + 32768;                       // 2 MB packed f16 x
    char*   af  = ws + 32768 + (size_t)NN * DD * 2; // 2 MB packed f16 a*C2

    conv_diag_kernel<<<1024, 256, 0, stream>>>((const float4*)x, (const float4*)a,
                                               xf, af, s1p, s3p);
    gemm_exp_sum<<<1024, 256, 0, stream>>>((const f16x8*)xf, (const f16x8*)af, s2p);
    finalize_kernel<<<1, 1024, 0, stream>>>(s1p, s3p, s2p, out);
}